// Round 6
// baseline (184.060 us; speedup 1.0000x reference)
//
#include <hip/hip_runtime.h>

// Flow1: RealNVP coupling flow. K=32 B=4096 ZS=128 ZH=64 HS=50 NF=2.
// Round 10: swapped-operand MFMA to kill the scalar-LDS round-trips.
// Evidence r9: occupancy pinned ~6 waves/CU (3 rounds running), VALUBusy 42%,
// 72 DS ops/step/lane of which 64 are scalar ds_write_b16 forced by the
// C/D layout (lane holds 4 rows x 1 col -> nothing packable).
// Trick: per-lane data of A-frag(X) == B-frag(X^T). Compute
//   H^T = W0 . Z^T   (instead of Z.W0^T),  MEW^T/SIG^T = W1/W2 . H^T
// -> same weight loads now serve as A-frags, same b128 LDS reads serve as
// B-frags, but D-output holds 1 row x 4 CONSECUTIVE cols per lane:
//  - H/active stores become packed ds_write_b64: 64 b16 -> 16 b64 per step
//  - biases become float4 loads; init/store become float4 (192 scalar
//    global loads/lane -> 48 f4 loads)
//  - T-reduce: 2 shuffles (xor 16, 32) instead of 4
// State layout now: lane (q,l15), tile t owns row rbase+t*16+l15, cols
// {nt*16+q*4+i}. logdet product regrouped 2x8 (>=1e-25, no underflow).
//
// Layouts (m89/m91-verified):
//   A-frag: A[m][k], m=lane&15, k=quad*8+j (j=0..7) per 32-K-tile
//   B-frag: B[k][n], n=lane&15, k=quad*8+j
//   C/D   : D[m][n], n=lane&15, m=quad*4+reg

typedef unsigned short ushort_t;
typedef unsigned int   uint_t;
typedef short bf8 __attribute__((ext_vector_type(8)));
typedef float f4  __attribute__((ext_vector_type(4)));

#define KK   32
#define BB   4096
#define ZSD  128
#define ZHD  64
#define HSD  50
#define NROWS (KK*BB)

#define WST  72                   // k-stride (shorts) for weight/act tiles
#define MATS (64*WST)             // shorts per padded matrix  = 4608
#define WGL_SHORTS (12*MATS)      // 55296 shorts = 110592 B
#define WS_BYTES   (WGL_SHORTS*2 + 768*4)   // + padded fp32 biases [4][3][64]

__device__ __forceinline__ float bf2f(ushort_t u){ union{uint_t i; float f;} v; v.i = ((uint_t)u)<<16; return v.f; }

// hardware bf16 convert (RNE on gfx950)
__device__ __forceinline__ ushort_t f2bf(float f){
  union{__bf16 h; ushort_t u;} v; v.h = (__bf16)f; return v.u;
}

// pack 4 floats -> 4 bf16 in a uint2 (one ds_write_b64)
__device__ __forceinline__ uint2 pack4(float a, float b, float c, float d){
  uint2 r;
  r.x = (uint_t)f2bf(a) | ((uint_t)f2bf(b) << 16);
  r.y = (uint_t)f2bf(c) | ((uint_t)f2bf(d) << 16);
  return r;
}

__device__ __forceinline__ float rcp_fast(float x){ return __builtin_amdgcn_rcpf(x); }

__device__ __forceinline__ float tanh_fast(float x){
  float ax = fabsf(x);
  float t  = __expf(-2.0f*ax);                  // (0,1]
  float r  = (1.0f - t) * rcp_fast(1.0f + t);
  union{float f; uint_t i;} u, s; u.f = r; s.f = x;
  u.i |= (s.i & 0x80000000u);
  return u.f;
}

// sigmoid only (log handled via product accumulation outside)
__device__ __forceinline__ float sigmoid_fast(float x){
  float ax  = fabsf(x);
  float e   = __expf(-ax);
  float inv = rcp_fast(1.0f + e);
  return (x >= 0.0f) ? inv : e*inv;
}

__device__ __forceinline__ f4 MFMA(bf8 a, bf8 b, f4 c){
  return __builtin_amdgcn_mfma_f32_16x16x32_bf16(a, b, c, 0, 0, 0);
}

// ---- weight preconversion: fp32 -> padded bf16 [step][mat][n][WST] + biases
// storage[n][k]: mat0 = W0[h=n][z=k], mat1 = W1[z=n][h=k], mat2 = W2[z=n][h=k]
// (works as B-frag for the old orientation AND as A-frag for the swapped one)
__global__ void convert_weights(const float* __restrict__ W0g,
                                const float* __restrict__ b0g,
                                const float* __restrict__ W1g,
                                const float* __restrict__ b1g,
                                const float* __restrict__ W2g,
                                const float* __restrict__ b2g,
                                ushort_t* __restrict__ wgl)
{
  int t = blockIdx.x*256 + threadIdx.x;
  if (t < WGL_SHORTS){
    int mi  = t / MATS;             // step*3 + which
    int rem = t % MATS;
    int n   = rem / WST;
    int k   = rem % WST;
    int step  = mi / 3;
    int which = mi % 3;
    float v = 0.0f;
    if (which == 0){
      if (n < HSD && k < ZHD) v = W0g[(step*HSD + n)*ZHD + k];
    } else if (which == 1){
      if (k < HSD)            v = W1g[(step*ZHD + n)*HSD + k];
    } else {
      if (k < HSD)            v = W2g[(step*ZHD + n)*HSD + k];
    }
    wgl[t] = f2bf(v);
  }
  if (t < 768){                                // biases fp32 padded to 64
    float* bp = (float*)(wgl + WGL_SHORTS);
    int step  = t / 192;
    int rem   = t % 192;
    int which = rem / 64;
    int n     = rem % 64;
    float v = 0.0f;
    if (which == 0){ if (n < HSD) v = b0g[step*HSD + n]; }
    else if (which == 1) v = b1g[step*ZHD + n];
    else                 v = b2g[step*ZHD + n];
    bp[t] = v;
  }
}

// one coupling step (swapped operands); pz = passive-half regs (2 tiles,
// row-per-lane D-layout), active halves already in zAw (row-major bf16).
__device__ __forceinline__ void do_step(
    int s, float (&pz)[2][16], float (&T)[2],
    ushort_t* zAw, ushort_t* hAw,
    const ushort_t* wgl, const float* wsb,
    int quad, int l15, int wr)
{
  const ushort_t* ws = wgl + (size_t)(s*3)*MATS;
  const float* bp0 = wsb + (s*3+0)*64;
  const float* bp1 = wsb + (s*3+1)*64;
  const float* bp2 = wsb + (s*3+2)*64;
  const int qc = quad*4;

  // ---- active B-frags (B-frag(Z^T) == A-frag(Z): row-major b128 reads) ----
  bf8 zf[2][2];
  #pragma unroll
  for (int t=0;t<2;++t)
    #pragma unroll
    for (int kt=0;kt<2;++kt)
      zf[t][kt] = *(const bf8*)(zAw + (t*16 + l15)*WST + kt*32 + quad*8);

  // ---- phase A: H^T = W0 . Z^T ; h = tanh(. + b0) ----
  float hrow[2][16];
  #pragma unroll
  for (int nt=0;nt<4;++nt){
    const ushort_t* wb = ws + (0*64 + nt*16 + l15)*WST + quad*8;   // A-frag(W0)
    bf8 a0  = *(const bf8*)(wb);
    bf8 a0b = *(const bf8*)(wb + 32);
    f4 b0v  = *(const f4*)(bp0 + nt*16 + qc);
    #pragma unroll
    for (int t=0;t<2;++t){
      f4 acc = {0.f,0.f,0.f,0.f};
      acc = MFMA(a0,  zf[t][0], acc);
      acc = MFMA(a0b, zf[t][1], acc);
      #pragma unroll
      for (int i=0;i<4;++i)
        hrow[t][nt*4+i] = tanh_fast(acc[i] + b0v[i]);
    }
  }

  // ---- H -> LDS (packed b64, row-major), then B-frags(H^T) ----
  #pragma unroll
  for (int t=0;t<2;++t)
    #pragma unroll
    for (int nt=0;nt<4;++nt)
      *(uint2*)(hAw + (t*16 + l15)*WST + nt*16 + qc) =
        pack4(hrow[t][nt*4+0], hrow[t][nt*4+1], hrow[t][nt*4+2], hrow[t][nt*4+3]);

  bf8 hf[2][2];
  #pragma unroll
  for (int t=0;t<2;++t)
    #pragma unroll
    for (int kt=0;kt<2;++kt)
      hf[t][kt] = *(const bf8*)(hAw + (t*16 + l15)*WST + kt*32 + quad*8);

  // ---- phase B: MEW^T = W1.H^T + b1 ; SIG^T = sigmoid(W2.H^T + b2) ----
  float spa[2] = {1.0f, 1.0f}, spb[2] = {1.0f, 1.0f};
  #pragma unroll
  for (int nt=0;nt<4;++nt){
    const ushort_t* w1p = ws + (1*64 + nt*16 + l15)*WST + quad*8;  // A-frag(W1)
    const ushort_t* w2p = ws + (2*64 + nt*16 + l15)*WST + quad*8;  // A-frag(W2)
    bf8 a1  = *(const bf8*)(w1p);
    bf8 a1b = *(const bf8*)(w1p + 32);
    bf8 a2  = *(const bf8*)(w2p);
    bf8 a2b = *(const bf8*)(w2p + 32);
    f4 b1v = *(const f4*)(bp1 + nt*16 + qc);
    f4 b2v = *(const f4*)(bp2 + nt*16 + qc);
    #pragma unroll
    for (int t=0;t<2;++t){
      f4 am = {0.f,0.f,0.f,0.f};
      f4 as = {0.f,0.f,0.f,0.f};
      am = MFMA(a1,  hf[t][0], am);
      am = MFMA(a1b, hf[t][1], am);
      as = MFMA(a2,  hf[t][0], as);
      as = MFMA(a2b, hf[t][1], as);
      #pragma unroll
      for (int i=0;i<4;++i){
        float mew  = am[i] + b1v[i];
        float spre = as[i] + b2v[i];
        float sig  = sigmoid_fast(spre);
        if (nt < 2) spa[t] *= sig; else spb[t] *= sig;
        pz[t][nt*4+i] = fmaf(pz[t][nt*4+i], sig, mew);
      }
    }
  }
  // 8-term products >= (7.5e-4)^8 ~ 1e-25: safely above fp32 underflow
  #pragma unroll
  for (int t=0;t<2;++t)
    T[t] += __logf(spa[t]) + __logf(spb[t]);

  // new active = just-updated passive -> zA (packed b64, row-major)
  if (wr){
    #pragma unroll
    for (int t=0;t<2;++t)
      #pragma unroll
      for (int nt=0;nt<4;++nt)
        *(uint2*)(zAw + (t*16 + l15)*WST + nt*16 + qc) =
          pack4(pz[t][nt*4+0], pz[t][nt*4+1], pz[t][nt*4+2], pz[t][nt*4+3]);
  }
}

__global__ __launch_bounds__(128) void flow_mfma(
    const float* __restrict__ mean, const float* __restrict__ logvar,
    const float* __restrict__ eps,
    const ushort_t* __restrict__ wgl,
    float* __restrict__ out)
{
  __shared__ __align__(16) ushort_t zA[2][32*WST];      // 2 x 4608 B
  __shared__ __align__(16) ushort_t hA[2][32*WST];      // 2 x 4608 B

  const int tid  = threadIdx.x;
  const int wave = tid >> 6;
  const int lane = tid & 63;
  const int quad = lane >> 4;
  const int l15  = lane & 15;
  const int qc   = quad*4;
  const int rbase = blockIdx.x*64 + wave*32;

  const float* wsb = (const float*)(wgl + WGL_SHORTS);
  ushort_t* zAw = zA[wave];
  ushort_t* hAw = hA[wave];

  // row-per-lane state: z1D[t][nt*4+i] = row rbase+t*16+l15,
  // col (within half) nt*16+qc+i
  float z1D[2][16], z2D[2][16];
  float T[2];                        // 0.5*sum(lv+eps^2) + sum(log sig), partial

  // ---- init: z = eps*exp(0.5*lv)+mean, float4 loads in new layout ----
  #pragma unroll
  for (int t=0;t<2;++t){
    int rrow = rbase + t*16 + l15;
    int brow = rrow & (BB-1);
    const float* er = eps    + (size_t)rrow*ZSD;
    const float* mr = mean   + (size_t)brow*ZSD;
    const float* vr = logvar + (size_t)brow*ZSD;
    float acc = 0.f;
    #pragma unroll
    for (int nt=0;nt<4;++nt){
      int c1 = nt*16 + qc;
      int c2 = 64 + c1;
      f4 e1 = *(const f4*)(er + c1), v1 = *(const f4*)(vr + c1), m1 = *(const f4*)(mr + c1);
      f4 e2 = *(const f4*)(er + c2), v2 = *(const f4*)(vr + c2), m2 = *(const f4*)(mr + c2);
      #pragma unroll
      for (int i=0;i<4;++i){
        z1D[t][nt*4+i] = fmaf(e1[i], __expf(0.5f*v1[i]), m1[i]);
        z2D[t][nt*4+i] = fmaf(e2[i], __expf(0.5f*v2[i]), m2[i]);
        acc += (v1[i] + e1[i]*e1[i]) + (v2[i] + e2[i]*e2[i]);
      }
    }
    T[t] = 0.5f*acc;
  }

  // initial active = z1 -> zA (packed b64)
  #pragma unroll
  for (int t=0;t<2;++t)
    #pragma unroll
    for (int nt=0;nt<4;++nt)
      *(uint2*)(zAw + (t*16 + l15)*WST + nt*16 + qc) =
        pack4(z1D[t][nt*4+0], z1D[t][nt*4+1], z1D[t][nt*4+2], z1D[t][nt*4+3]);

  // ---- 4 coupling steps (2 bodies in a non-unrolled loop to bound I$) ----
  #pragma unroll 1
  for (int it=0; it<2; ++it){
    do_step(2*it+0, z2D, T, zAw, hAw, wgl, wsb, quad, l15, 1);
    do_step(2*it+1, z1D, T, zAw, hAw, wgl, wsb, quad, l15, it==0);
  }

  // ---- store z_out (fp32, float4) ----
  #pragma unroll
  for (int t=0;t<2;++t){
    int rrow = rbase + t*16 + l15;
    float* orow = out + (size_t)rrow*ZSD;
    #pragma unroll
    for (int nt=0;nt<4;++nt){
      f4 o1 = {z1D[t][nt*4+0], z1D[t][nt*4+1], z1D[t][nt*4+2], z1D[t][nt*4+3]};
      f4 o2 = {z2D[t][nt*4+0], z2D[t][nt*4+1], z2D[t][nt*4+2], z2D[t][nt*4+3]};
      *(f4*)(orow + nt*16 + qc)      = o1;
      *(f4*)(orow + 64 + nt*16 + qc) = o2;
    }
  }

  // ---- logpz: reduce T over the 4 quads (cols partitioned by quad) ----
  #pragma unroll
  for (int t=0;t<2;++t){
    float v = T[t];
    v += __shfl_xor(v, 16, 64);
    v += __shfl_xor(v, 32, 64);
    T[t] = v;
  }
  if (lane < 16){
    const float NC = -0.5f * 128.0f * 1.8378770664093453f;
    #pragma unroll
    for (int t=0;t<2;++t)
      out[(size_t)NROWS*ZSD + rbase + t*16 + l15] = NC - T[t];
  }
}

extern "C" void kernel_launch(void* const* d_in, const int* in_sizes, int n_in,
                              void* d_out, int out_size, void* d_ws, size_t ws_size,
                              hipStream_t stream)
{
  const float* mean   = (const float*)d_in[0];
  const float* logvar = (const float*)d_in[1];
  const float* eps    = (const float*)d_in[2];
  const float* W0     = (const float*)d_in[3];
  const float* b0     = (const float*)d_in[4];
  const float* W1     = (const float*)d_in[5];
  const float* b1     = (const float*)d_in[6];
  const float* W2     = (const float*)d_in[7];
  const float* b2     = (const float*)d_in[8];
  ushort_t* wgl = (ushort_t*)d_ws;          // ws_size >= 156448 proven round 3

  convert_weights<<<(WGL_SHORTS + 255)/256, 256, 0, stream>>>(W0,b0,W1,b1,W2,b2, wgl);
  flow_mfma<<<NROWS/64, 128, 0, stream>>>(mean, logvar, eps, wgl, (float*)d_out);
}